// Round 5
// baseline (349.586 us; speedup 1.0000x reference)
//
#include <hip/hip_runtime.h>
#include <math.h>

// Workspace layout (floats):
//   gsum_part[8][81*33] @ 0      partial histograms: cols 0-31 = sum(z_hyp), col 32 = count
//   dsum_part[8][81*4]  @ 21384  partial per-(s4,level) distance sums
//   cent   [120*32]     @ 23976  centroids (lvl1:0-2, lvl2:3-11, lvl3:12-38, lvl4:39-119)
//   cnt_all[120]        @ 27816
//   cnorm  [120]        @ 27936  stores (1 - ||centroid||^2)
// First 23976 floats are accumulators -> memset to 0 each launch.

#define MAXR  0.95f
#define MAXR2 0.9025f
#define LN2F  0.6931471805599453f

__device__ __forceinline__ float fsqrt(float x) { return __builtin_amdgcn_sqrtf(x); }
__device__ __forceinline__ float frcp(float x)  { return __builtin_amdgcn_rcpf(x); }
__device__ __forceinline__ float frsq(float x)  { return __builtin_amdgcn_rsqf(x); }

// 8-lane sum reduction entirely in the VALU pipe via DPP:
// quad_perm xor1 = 0xB1, xor2 = 0x4E, cross-quad = row_half_mirror 0x141.
__device__ __forceinline__ float red8_dpp(float v) {
    v += __int_as_float(__builtin_amdgcn_update_dpp(0, __float_as_int(v), 0xB1, 0xF, 0xF, 1));
    v += __int_as_float(__builtin_amdgcn_update_dpp(0, __float_as_int(v), 0x4E, 0xF, 0xF, 1));
    v += __int_as_float(__builtin_amdgcn_update_dpp(0, __float_as_int(v), 0x141, 0xF, 0xF, 1));
    return v;
}

__device__ __forceinline__ float red32(float v) {
    v += __shfl_xor(v, 1, 32);
    v += __shfl_xor(v, 2, 32);
    v += __shfl_xor(v, 4, 32);
    v += __shfl_xor(v, 8, 32);
    v += __shfl_xor(v, 16, 32);
    return v;
}

// Pass 1: level-4 histogram (vector sums + counts) of projected points.
// 8 lanes/point, 4 points per wave-iter batched; fire-and-forget ds_add_f32
// into one LDS copy (no rank rounds, no read-back). Row stride 36.
__global__ __launch_bounds__(256) void pass1_hist(
        const float* __restrict__ z, const int* __restrict__ idx,
        float* __restrict__ gsum, int B) {
    __shared__ float lsum[81][36];   // col 32 = count, 33-35 pad
    const int tid = threadIdx.x;
    for (int j = tid; j < 81 * 36; j += 256) (&lsum[0][0])[j] = 0.f;
    __syncthreads();

    const int w = tid >> 6;
    const int g = (tid >> 3) & 7;
    const int sub = tid & 7;
    const int STRIDE = gridDim.x * 128;
    const int base0 = blockIdx.x * 128 + w * 32 + g;
    const int nfull = B / STRIDE;

    for (int it = 0; it < nfull; ++it) {
        const int ib = it * STRIDE + base0;
        float4 xv[4];
        int s4v[4];
#pragma unroll
        for (int b = 0; b < 4; ++b)
            xv[b] = *(const float4*)(z + (size_t)(ib + b * 8) * 32 + sub * 4);
#pragma unroll
        for (int b = 0; b < 4; ++b)
            s4v[b] = idx[ib + b * 8] / 243;
#pragma unroll
        for (int b = 0; b < 4; ++b) {
            const float nx = red8_dpp(xv[b].x * xv[b].x + xv[b].y * xv[b].y +
                                      xv[b].z * xv[b].z + xv[b].w * xv[b].w);
            const float s = (nx > MAXR2) ? MAXR * frsq(nx) : 1.0f;
            xv[b].x *= s; xv[b].y *= s; xv[b].z *= s; xv[b].w *= s;
        }
#pragma unroll
        for (int b = 0; b < 4; ++b) {
            float* row = &lsum[s4v[b]][0];
            unsafeAtomicAdd(&row[sub * 4 + 0], xv[b].x);
            unsafeAtomicAdd(&row[sub * 4 + 1], xv[b].y);
            unsafeAtomicAdd(&row[sub * 4 + 2], xv[b].z);
            unsafeAtomicAdd(&row[sub * 4 + 3], xv[b].w);
            if (sub == 0) unsafeAtomicAdd(&row[32], 1.0f);
        }
    }
    // generic tail (not executed for B = 1M with grid 1024)
    if (B % STRIDE) {
        const int ib = nfull * STRIDE + base0;
        for (int b = 0; b < 4; ++b) {
            const int i = ib + b * 8;
            if (i >= B) continue;
            float4 xv = *(const float4*)(z + (size_t)i * 32 + sub * 4);
            const int s4 = idx[i] / 243;
            const float nx = red8_dpp(xv.x * xv.x + xv.y * xv.y +
                                      xv.z * xv.z + xv.w * xv.w);
            const float s = (nx > MAXR2) ? MAXR * frsq(nx) : 1.0f;
            float* row = &lsum[s4][0];
            unsafeAtomicAdd(&row[sub * 4 + 0], xv.x * s);
            unsafeAtomicAdd(&row[sub * 4 + 1], xv.y * s);
            unsafeAtomicAdd(&row[sub * 4 + 2], xv.z * s);
            unsafeAtomicAdd(&row[sub * 4 + 3], xv.w * s);
            if (sub == 0) unsafeAtomicAdd(&row[32], 1.0f);
        }
    }
    __syncthreads();
    float* gpart = gsum + (blockIdx.x & 7) * 2673;
    for (int j = tid; j < 81 * 33; j += 256) {
        const int r = j / 33, c = j - r * 33;
        unsafeAtomicAdd(&gpart[j], lsum[r][c]);
    }
}

// Pass 2: aggregate hierarchy + Frechet-mean iteration for all 120 segments.
__global__ __launch_bounds__(256) void pass2_centroids(
        const float* __restrict__ gsum,
        float* __restrict__ cent, float* __restrict__ cnt_all,
        float* __restrict__ cnorm) {
    const int tid = threadIdx.x;
    const int lane = tid & 31;
    const int grp = tid >> 5;
    for (int t = grp; t < 120; t += (blockDim.x >> 5)) {
        int c0, n;
        if (t < 3)       { c0 = t * 27;        n = 27; }
        else if (t < 12) { c0 = (t - 3) * 9;   n = 9;  }
        else if (t < 39) { c0 = (t - 12) * 3;  n = 3;  }
        else             { c0 = (t - 39);      n = 1;  }
        float sum = 0.f, cnt = 0.f;
        for (int k = 0; k < 8; ++k) {
            const float* gp = gsum + k * 2673;
            for (int kk = 0; kk < n; ++kk) {
                sum += gp[(c0 + kk) * 33 + lane];
                cnt += gp[(c0 + kk) * 33 + 32];
            }
        }
        const float em = sum / fmaxf(cnt, 1.0f);
        float m = em;
        {
            float norm = sqrtf(red32(m * m));
            if (norm > MAXR) m *= MAXR / (norm + 1e-12f);
        }
        for (int it = 0; it < 10; ++it) {
            float v = m + 0.1f * (em - m);
            float norm = sqrtf(red32(v * v));
            if (norm > MAXR) v *= MAXR / (norm + 1e-12f);
            m = v;
        }
        cent[t * 32 + lane] = m;
        float ny = red32(m * m);
        if (lane == 0) { cnt_all[t] = cnt; cnorm[t] = 1.0f - ny; }
    }
}

// Pass 3: per-point distances to 4 ancestor centroids, batched x4, DPP
// reductions, dot-product distance form, fire-and-forget LDS atomics.
// dl holds log2 form; ln2 applied once in pass4.
__global__ __launch_bounds__(256) void pass3_dist(
        const float* __restrict__ z, const int* __restrict__ idx,
        const float* __restrict__ cent, const float* __restrict__ cnorm,
        float* __restrict__ dsum, int B) {
    __shared__ float lcent[120 * 32];
    __shared__ float lcn[120];          // (1 - ny)
    __shared__ float ld[81 * 4];
    const int tid = threadIdx.x;
    for (int j = tid; j < 120 * 32; j += 256) lcent[j] = cent[j];
    for (int j = tid; j < 120; j += 256) lcn[j] = cnorm[j];
    for (int j = tid; j < 81 * 4; j += 256) ld[j] = 0.f;
    __syncthreads();

    const int w = tid >> 6;
    const int g = (tid >> 3) & 7;
    const int sub = tid & 7;
    const int STRIDE = gridDim.x * 128;
    const int base0 = blockIdx.x * 128 + w * 32 + g;
    const int nfull = B / STRIDE;

    for (int it = 0; it < nfull; ++it) {
        const int ib = it * STRIDE + base0;
        float4 xv[4];
        int s4v[4];
#pragma unroll
        for (int b = 0; b < 4; ++b)
            xv[b] = *(const float4*)(z + (size_t)(ib + b * 8) * 32 + sub * 4);
#pragma unroll
        for (int b = 0; b < 4; ++b)
            s4v[b] = idx[ib + b * 8] / 243;
#pragma unroll
        for (int b = 0; b < 4; ++b) {
            float nx = red8_dpp(xv[b].x * xv[b].x + xv[b].y * xv[b].y +
                                xv[b].z * xv[b].z + xv[b].w * xv[b].w);
            const float s = (nx > MAXR2) ? MAXR * frsq(nx) : 1.0f;
            xv[b].x *= s; xv[b].y *= s; xv[b].z *= s; xv[b].w *= s;
            nx = nx * s * s;
            const float ah = 0.5f * (1.0f - nx);   // (1-nx)/2
            const float c2a = 1.0f + nx;           // 2 - (1-nx)
            const int s4 = s4v[b];
            const int d3 = s4 / 3, d9 = d3 / 3, d27 = d9 / 3;
            const int tl[4] = {d27, 3 + d9, 12 + d3, 39 + s4};
            float dls[4];
#pragma unroll
            for (int l = 0; l < 4; ++l) {
                const int t = tl[l];
                const float4 c = *(const float4*)(lcent + t * 32 + sub * 4);
                const float dot = red8_dpp(xv[b].x * c.x + xv[b].y * c.y +
                                           xv[b].z * c.z + xv[b].w * c.w);
                const float bny = lcn[t];
                // sq = nx + ny - 2dot = (c2a - bny) - 2dot
                const float sq = fmaf(-2.0f, dot, c2a - bny);
                const float d = fmaxf(ah * bny, 5e-13f);   // denom/2
                float tt = sq * frcp(d);
                tt = fmaxf(tt, 1e-7f);
                // acosh(1+tt) = ln(1 + tt + sqrt(tt*(tt+2)))
                dls[l] = __log2f(1.0f + tt + fsqrt(tt * (tt + 2.0f)));
            }
            // lanes 0..3 of each group add level sub to ld[s4*4+sub]
            const float dsel = (sub & 2) ? ((sub & 1) ? dls[3] : dls[2])
                                         : ((sub & 1) ? dls[1] : dls[0]);
            if (sub < 4) unsafeAtomicAdd(&ld[s4 * 4 + sub], dsel);
        }
    }
    // generic tail (not executed for B = 1M with grid 2048)
    if (B % STRIDE) {
        const int ib = nfull * STRIDE + base0;
        for (int b = 0; b < 4; ++b) {
            const int i = ib + b * 8;
            if (i >= B) continue;
            float4 xv = *(const float4*)(z + (size_t)i * 32 + sub * 4);
            const int s4 = idx[i] / 243;
            float nx = red8_dpp(xv.x * xv.x + xv.y * xv.y + xv.z * xv.z + xv.w * xv.w);
            const float s = (nx > MAXR2) ? MAXR * frsq(nx) : 1.0f;
            xv.x *= s; xv.y *= s; xv.z *= s; xv.w *= s;
            nx = nx * s * s;
            const float ah = 0.5f * (1.0f - nx);
            const float c2a = 1.0f + nx;
            const int d3 = s4 / 3, d9 = d3 / 3, d27 = d9 / 3;
            const int tl[4] = {d27, 3 + d9, 12 + d3, 39 + s4};
            float dls[4];
#pragma unroll
            for (int l = 0; l < 4; ++l) {
                const int t = tl[l];
                const float4 c = *(const float4*)(lcent + t * 32 + sub * 4);
                const float dot = red8_dpp(xv.x * c.x + xv.y * c.y +
                                           xv.z * c.z + xv.w * c.w);
                const float bny = lcn[t];
                const float sq = fmaf(-2.0f, dot, c2a - bny);
                const float d = fmaxf(ah * bny, 5e-13f);
                float tt = sq * frcp(d);
                tt = fmaxf(tt, 1e-7f);
                dls[l] = __log2f(1.0f + tt + fsqrt(tt * (tt + 2.0f)));
            }
            const float dsel = (sub & 2) ? ((sub & 1) ? dls[3] : dls[2])
                                         : ((sub & 1) ? dls[1] : dls[0]);
            if (sub < 4) unsafeAtomicAdd(&ld[s4 * 4 + sub], dsel);
        }
    }
    __syncthreads();
    float* dpart = dsum + (blockIdx.x & 7) * 324;
    for (int j = tid; j < 81 * 4; j += 256)
        unsafeAtomicAdd(&dpart[j], ld[j]);
}

// Pass 4: finalize — aggregate per-level, apply valid/count logic + ln2,
// weighted sum.
__global__ __launch_bounds__(128) void pass4_final(
        const float* __restrict__ dsum, const float* __restrict__ cnt_all,
        const float* __restrict__ w, float* __restrict__ out) {
    __shared__ float sl[81];
    __shared__ float su[81];
    const int tid = threadIdx.x;
    const int toff[4] = {0, 3, 12, 39};
    const int nsegs[4] = {3, 9, 27, 81};
    float total = 0.f;
    for (int l = 0; l < 4; ++l) {
        const int n_seg = nsegs[l];
        const int ch = 81 / n_seg;
        __syncthreads();
        if (tid < n_seg) {
            float cnt = cnt_all[toff[l] + tid];
            float ds = 0.f;
            for (int p = 0; p < 8; ++p)
                for (int k = 0; k < ch; ++k)
                    ds += dsum[p * 324 + (tid * ch + k) * 4 + l];
            sl[tid] = (cnt >= 2.0f) ? ds * LN2F / fmaxf(cnt, 1.0f) : 0.f;
            su[tid] = (cnt > 0.0f) ? 1.f : 0.f;
        }
        __syncthreads();
        if (tid == 0) {
            float ll = 0.f, nu = 0.f;
            for (int s = 0; s < n_seg; ++s) { ll += sl[s]; nu += su[s]; }
            total += w[l] * ll / fmaxf(nu, 1.0f);
        }
    }
    if (tid == 0) out[0] = total;
}

extern "C" void kernel_launch(void* const* d_in, const int* in_sizes, int n_in,
                              void* d_out, int out_size, void* d_ws, size_t ws_size,
                              hipStream_t stream) {
    const float* z   = (const float*)d_in[0];
    const int*   idx = (const int*)d_in[1];
    const float* w   = (const float*)d_in[2];
    float* out = (float*)d_out;
    float* ws  = (float*)d_ws;
    const int B = in_sizes[1];

    float* gsum    = ws;           // 8*2673 = 21384
    float* dsum    = ws + 21384;   // 8*324  = 2592
    float* cent    = ws + 23976;   // 3840
    float* cnt_all = ws + 27816;   // 120
    float* cnorm   = ws + 27936;   // 120

    hipMemsetAsync(ws, 0, 23976 * sizeof(float), stream);
    pass1_hist<<<1024, 256, 0, stream>>>(z, idx, gsum, B);
    pass2_centroids<<<1, 256, 0, stream>>>(gsum, cent, cnt_all, cnorm);
    pass3_dist<<<2048, 256, 0, stream>>>(z, idx, cent, cnorm, dsum, B);
    pass4_final<<<1, 128, 0, stream>>>(dsum, cnt_all, w, out);
}

// Round 6
// 215.147 us; speedup vs baseline: 1.6249x; 1.6249x over previous
//
#include <hip/hip_runtime.h>
#include <math.h>

// Workspace layout (floats):
//   gsum_part[8][81*33] @ 0      partial histograms: cols 0-31 = sum(z_hyp), col 32 = count
//   dsum_part[8][81*4]  @ 21384  partial per-(s4,level) distance sums
//   cent   [120*32]     @ 23976  centroids (lvl1:0-2, lvl2:3-11, lvl3:12-38, lvl4:39-119)
//   cnt_all[120]        @ 27816
//   cnorm  [120]        @ 27936  stores (1 - ||centroid||^2)
// First 23976 floats are accumulators -> memset to 0 each launch.
//
// HW note (measured R2/R4/R5): LDS atomics (ds_add_f32) are lane-serial
// (~5 cy/active lane) on gfx950 -> NEVER use them in hot loops. Exec-wide
// non-atomic ds_read_b128/ds_write_b128 RMW with rank-round duplicate
// serialization is ~10x faster.

#define MAXR  0.95f
#define MAXR2 0.9025f
#define LN2F  0.6931471805599453f

__device__ __forceinline__ float fsqrt(float x) { return __builtin_amdgcn_sqrtf(x); }
__device__ __forceinline__ float frcp(float x)  { return __builtin_amdgcn_rcpf(x); }
__device__ __forceinline__ float frsq(float x)  { return __builtin_amdgcn_rsqf(x); }

// 8-lane sum reduction entirely in the VALU pipe via DPP:
// quad_perm xor1 = 0xB1, xor2 = 0x4E, cross-quad = row_half_mirror 0x141.
__device__ __forceinline__ float red8_dpp(float v) {
    v += __int_as_float(__builtin_amdgcn_update_dpp(0, __float_as_int(v), 0xB1, 0xF, 0xF, 1));
    v += __int_as_float(__builtin_amdgcn_update_dpp(0, __float_as_int(v), 0x4E, 0xF, 0xF, 1));
    v += __int_as_float(__builtin_amdgcn_update_dpp(0, __float_as_int(v), 0x141, 0xF, 0xF, 1));
    return v;
}

__device__ __forceinline__ float red32(float v) {
    v += __shfl_xor(v, 1, 32);
    v += __shfl_xor(v, 2, 32);
    v += __shfl_xor(v, 4, 32);
    v += __shfl_xor(v, 8, 32);
    v += __shfl_xor(v, 16, 32);
    return v;
}

// rank of this 8-lane group among same-s4 groups in the wave (RMW rounds).
__device__ __forceinline__ int dup_rank(int s4, int g, int sub) {
    int sj = __shfl(s4, sub * 8, 64);
    unsigned long long eq = __ballot(sj == s4);
    unsigned int row = (unsigned int)(eq >> (g * 8));
    return __popc(row & ((1u << g) - 1u));
}

// Pass 1: level-4 histogram (vector sums + counts) of projected points.
// 8 lanes/point, 4 points per wave-iter batched for ILP/MLP; DPP reductions;
// per-WAVE private LDS copy, non-atomic RMW with rank-round duplicate
// serialization. Row stride 36 floats (144 B, b128-aligned); col 32 = count.
__global__ __launch_bounds__(256) void pass1_hist(
        const float* __restrict__ z, const int* __restrict__ idx,
        float* __restrict__ gsum, int B) {
    __shared__ float lsum[4][81][36];
    const int tid = threadIdx.x;
    for (int j = tid; j < 4 * 81 * 36; j += 256) (&lsum[0][0][0])[j] = 0.f;
    __syncthreads();

    const int w = tid >> 6;
    const int g = (tid & 63) >> 3;
    const int sub = tid & 7;
    const int STRIDE = gridDim.x * 128;
    const int base0 = blockIdx.x * 128 + w * 32 + g;
    const int nfull = B / STRIDE;
    float* const lw = &lsum[w][0][0];

    for (int it = 0; it < nfull; ++it) {
        const int ib = it * STRIDE + base0;
        float4 xv[4];
        int s4v[4], rank[4];
#pragma unroll
        for (int b = 0; b < 4; ++b)
            xv[b] = *(const float4*)(z + (size_t)(ib + b * 8) * 32 + sub * 4);
#pragma unroll
        for (int b = 0; b < 4; ++b)
            s4v[b] = idx[ib + b * 8] / 243;
#pragma unroll
        for (int b = 0; b < 4; ++b) {
            const float nx = red8_dpp(xv[b].x * xv[b].x + xv[b].y * xv[b].y +
                                      xv[b].z * xv[b].z + xv[b].w * xv[b].w);
            const float s = (nx > MAXR2) ? MAXR * frsq(nx) : 1.0f;
            xv[b].x *= s; xv[b].y *= s; xv[b].z *= s; xv[b].w *= s;
        }
#pragma unroll
        for (int b = 0; b < 4; ++b)
            rank[b] = dup_rank(s4v[b], g, sub);
#pragma unroll
        for (int b = 0; b < 4; ++b) {
            float* row = lw + s4v[b] * 36;
            for (int r = 0;; ++r) {
                if (!__any(rank[b] == r)) break;
                if (rank[b] == r) {
                    float4 cur = *(float4*)(row + sub * 4);
                    cur.x += xv[b].x; cur.y += xv[b].y;
                    cur.z += xv[b].z; cur.w += xv[b].w;
                    *(float4*)(row + sub * 4) = cur;
                    if (sub == 0) row[32] += 1.0f;
                }
            }
        }
    }
    // generic tail (not executed for B = 1M with grid 1024)
    if (B % STRIDE) {
        const int ib = nfull * STRIDE + base0;
        for (int b = 0; b < 4; ++b) {
            const int i = ib + b * 8;
            const bool act = i < B;
            float4 xv = act ? *(const float4*)(z + (size_t)i * 32 + sub * 4)
                            : make_float4(0.f, 0.f, 0.f, 0.f);
            int s4 = act ? idx[i] / 243 : 81 + g;   // distinct dummy bins
            const float nx = red8_dpp(xv.x * xv.x + xv.y * xv.y +
                                      xv.z * xv.z + xv.w * xv.w);
            const float s = (nx > MAXR2) ? MAXR * frsq(nx) : 1.0f;
            xv.x *= s; xv.y *= s; xv.z *= s; xv.w *= s;
            int rank = dup_rank(s4, g, sub);
            for (int r = 0;; ++r) {
                if (!__any(rank == r)) break;
                if (act && rank == r) {
                    float* row = lw + s4 * 36;
                    float4 cur = *(float4*)(row + sub * 4);
                    cur.x += xv.x; cur.y += xv.y; cur.z += xv.z; cur.w += xv.w;
                    *(float4*)(row + sub * 4) = cur;
                    if (sub == 0) row[32] += 1.0f;
                }
            }
        }
    }
    __syncthreads();
    float* gpart = gsum + (blockIdx.x & 7) * 2673;
    for (int j = tid; j < 81 * 33; j += 256) {
        const int r = j / 33, c = j - r * 33;
        const float v = lsum[0][r][c] + lsum[1][r][c] +
                        lsum[2][r][c] + lsum[3][r][c];
        unsafeAtomicAdd(&gpart[j], v);
    }
}

// Pass 2: aggregate hierarchy + Frechet-mean iteration for all 120 segments.
__global__ __launch_bounds__(256) void pass2_centroids(
        const float* __restrict__ gsum,
        float* __restrict__ cent, float* __restrict__ cnt_all,
        float* __restrict__ cnorm) {
    const int tid = threadIdx.x;
    const int lane = tid & 31;
    const int grp = tid >> 5;
    for (int t = grp; t < 120; t += (blockDim.x >> 5)) {
        int c0, n;
        if (t < 3)       { c0 = t * 27;        n = 27; }
        else if (t < 12) { c0 = (t - 3) * 9;   n = 9;  }
        else if (t < 39) { c0 = (t - 12) * 3;  n = 3;  }
        else             { c0 = (t - 39);      n = 1;  }
        float sum = 0.f, cnt = 0.f;
        for (int k = 0; k < 8; ++k) {
            const float* gp = gsum + k * 2673;
            for (int kk = 0; kk < n; ++kk) {
                sum += gp[(c0 + kk) * 33 + lane];
                cnt += gp[(c0 + kk) * 33 + 32];
            }
        }
        const float em = sum / fmaxf(cnt, 1.0f);
        float m = em;
        {
            float norm = sqrtf(red32(m * m));
            if (norm > MAXR) m *= MAXR / (norm + 1e-12f);
        }
        for (int it = 0; it < 10; ++it) {
            float v = m + 0.1f * (em - m);
            float norm = sqrtf(red32(v * v));
            if (norm > MAXR) v *= MAXR / (norm + 1e-12f);
            m = v;
        }
        cent[t * 32 + lane] = m;
        float ny = red32(m * m);
        if (lane == 0) { cnt_all[t] = cnt; cnorm[t] = 1.0f - ny; }
    }
}

// Pass 3: per-point distances to 4 ancestor centroids, batched x4, DPP
// reductions, dot-product distance form (sq = nx+ny-2<x,c>), per-wave
// [81][4] LDS accumulator with rank-round float4 RMW (sub==0 lane).
// dl holds log2 form; ln2 applied once in pass4.
__global__ __launch_bounds__(256) void pass3_dist(
        const float* __restrict__ z, const int* __restrict__ idx,
        const float* __restrict__ cent, const float* __restrict__ cnorm,
        float* __restrict__ dsum, int B) {
    __shared__ float lcent[120 * 32];
    __shared__ float lcn[120];          // (1 - ny)
    __shared__ float ld[4][81][4];
    const int tid = threadIdx.x;
    for (int j = tid; j < 120 * 32; j += 256) lcent[j] = cent[j];
    for (int j = tid; j < 120; j += 256) lcn[j] = cnorm[j];
    for (int j = tid; j < 4 * 81 * 4; j += 256) (&ld[0][0][0])[j] = 0.f;
    __syncthreads();

    const int w = tid >> 6;
    const int g = (tid & 63) >> 3;
    const int sub = tid & 7;
    const int STRIDE = gridDim.x * 128;
    const int base0 = blockIdx.x * 128 + w * 32 + g;
    const int nfull = B / STRIDE;

    for (int it = 0; it < nfull; ++it) {
        const int ib = it * STRIDE + base0;
        float4 xv[4];
        int s4v[4], rank[4];
        float dl[4][4];
#pragma unroll
        for (int b = 0; b < 4; ++b)
            xv[b] = *(const float4*)(z + (size_t)(ib + b * 8) * 32 + sub * 4);
#pragma unroll
        for (int b = 0; b < 4; ++b)
            s4v[b] = idx[ib + b * 8] / 243;
#pragma unroll
        for (int b = 0; b < 4; ++b) {
            float nx = red8_dpp(xv[b].x * xv[b].x + xv[b].y * xv[b].y +
                                xv[b].z * xv[b].z + xv[b].w * xv[b].w);
            const float s = (nx > MAXR2) ? MAXR * frsq(nx) : 1.0f;
            xv[b].x *= s; xv[b].y *= s; xv[b].z *= s; xv[b].w *= s;
            nx = nx * s * s;
            const float ah = 0.5f * (1.0f - nx);   // (1-nx)/2
            const float c2a = 1.0f + nx;           // nx + 1
            const int s4 = s4v[b];
            const int d3 = s4 / 3, d9 = d3 / 3, d27 = d9 / 3;
            const int tl[4] = {d27, 3 + d9, 12 + d3, 39 + s4};
#pragma unroll
            for (int l = 0; l < 4; ++l) {
                const int t = tl[l];
                const float4 c = *(const float4*)(lcent + t * 32 + sub * 4);
                const float dot = red8_dpp(xv[b].x * c.x + xv[b].y * c.y +
                                           xv[b].z * c.z + xv[b].w * c.w);
                const float bny = lcn[t];
                // sq = nx + ny - 2dot = (c2a - bny) - 2dot
                const float sq = fmaf(-2.0f, dot, c2a - bny);
                const float d = fmaxf(ah * bny, 5e-13f);   // denom/2
                float tt = sq * frcp(d);
                tt = fmaxf(tt, 1e-7f);
                // acosh(1+tt) = ln(1 + tt + sqrt(tt*(tt+2)))
                dl[b][l] = __log2f(1.0f + tt + fsqrt(tt * (tt + 2.0f)));
            }
        }
#pragma unroll
        for (int b = 0; b < 4; ++b)
            rank[b] = dup_rank(s4v[b], g, sub);
#pragma unroll
        for (int b = 0; b < 4; ++b) {
            float* row = &ld[w][s4v[b]][0];
            for (int r = 0;; ++r) {
                if (!__any(rank[b] == r)) break;
                if (rank[b] == r && sub == 0) {
                    float4 cur = *(float4*)row;
                    cur.x += dl[b][0]; cur.y += dl[b][1];
                    cur.z += dl[b][2]; cur.w += dl[b][3];
                    *(float4*)row = cur;
                }
            }
        }
    }
    // generic tail (not executed for B = 1M with grid 2048)
    if (B % STRIDE) {
        const int ib = nfull * STRIDE + base0;
        for (int b = 0; b < 4; ++b) {
            const int i = ib + b * 8;
            const bool act = i < B;
            float4 xv = act ? *(const float4*)(z + (size_t)i * 32 + sub * 4)
                            : make_float4(0.f, 0.f, 0.f, 0.f);
            int s4 = act ? idx[i] / 243 : 81 + g;
            float nx = red8_dpp(xv.x * xv.x + xv.y * xv.y + xv.z * xv.z + xv.w * xv.w);
            const float s = (nx > MAXR2) ? MAXR * frsq(nx) : 1.0f;
            xv.x *= s; xv.y *= s; xv.z *= s; xv.w *= s;
            nx = nx * s * s;
            const float ah = 0.5f * (1.0f - nx);
            const float c2a = 1.0f + nx;
            const int ss = act ? s4 : 0;
            const int d3 = ss / 3, d9 = d3 / 3, d27 = d9 / 3;
            const int tl[4] = {d27, 3 + d9, 12 + d3, 39 + ss};
            float dl[4];
#pragma unroll
            for (int l = 0; l < 4; ++l) {
                const int t = tl[l];
                const float4 c = *(const float4*)(lcent + t * 32 + sub * 4);
                const float dot = red8_dpp(xv.x * c.x + xv.y * c.y +
                                           xv.z * c.z + xv.w * c.w);
                const float bny = lcn[t];
                const float sq = fmaf(-2.0f, dot, c2a - bny);
                const float d = fmaxf(ah * bny, 5e-13f);
                float tt = sq * frcp(d);
                tt = fmaxf(tt, 1e-7f);
                dl[l] = __log2f(1.0f + tt + fsqrt(tt * (tt + 2.0f)));
            }
            int rank = dup_rank(s4, g, sub);
            for (int r = 0;; ++r) {
                if (!__any(rank == r)) break;
                if (act && rank == r && sub == 0) {
                    float* row = &ld[w][s4][0];
                    float4 cur = *(float4*)row;
                    cur.x += dl[0]; cur.y += dl[1]; cur.z += dl[2]; cur.w += dl[3];
                    *(float4*)row = cur;
                }
            }
        }
    }
    __syncthreads();
    float* dpart = dsum + (blockIdx.x & 7) * 324;
    for (int j = tid; j < 81 * 4; j += 256) {
        const float v = (&ld[0][0][0])[j] + (&ld[1][0][0])[j] +
                        (&ld[2][0][0])[j] + (&ld[3][0][0])[j];
        unsafeAtomicAdd(&dpart[j], v);
    }
}

// Pass 4: finalize — aggregate per-level, apply valid/count logic + ln2,
// weighted sum.
__global__ __launch_bounds__(128) void pass4_final(
        const float* __restrict__ dsum, const float* __restrict__ cnt_all,
        const float* __restrict__ w, float* __restrict__ out) {
    __shared__ float sl[81];
    __shared__ float su[81];
    const int tid = threadIdx.x;
    const int toff[4] = {0, 3, 12, 39};
    const int nsegs[4] = {3, 9, 27, 81};
    float total = 0.f;
    for (int l = 0; l < 4; ++l) {
        const int n_seg = nsegs[l];
        const int ch = 81 / n_seg;
        __syncthreads();
        if (tid < n_seg) {
            float cnt = cnt_all[toff[l] + tid];
            float ds = 0.f;
            for (int p = 0; p < 8; ++p)
                for (int k = 0; k < ch; ++k)
                    ds += dsum[p * 324 + (tid * ch + k) * 4 + l];
            sl[tid] = (cnt >= 2.0f) ? ds * LN2F / fmaxf(cnt, 1.0f) : 0.f;
            su[tid] = (cnt > 0.0f) ? 1.f : 0.f;
        }
        __syncthreads();
        if (tid == 0) {
            float ll = 0.f, nu = 0.f;
            for (int s = 0; s < n_seg; ++s) { ll += sl[s]; nu += su[s]; }
            total += w[l] * ll / fmaxf(nu, 1.0f);
        }
    }
    if (tid == 0) out[0] = total;
}

extern "C" void kernel_launch(void* const* d_in, const int* in_sizes, int n_in,
                              void* d_out, int out_size, void* d_ws, size_t ws_size,
                              hipStream_t stream) {
    const float* z   = (const float*)d_in[0];
    const int*   idx = (const int*)d_in[1];
    const float* w   = (const float*)d_in[2];
    float* out = (float*)d_out;
    float* ws  = (float*)d_ws;
    const int B = in_sizes[1];

    float* gsum    = ws;           // 8*2673 = 21384
    float* dsum    = ws + 21384;   // 8*324  = 2592
    float* cent    = ws + 23976;   // 3840
    float* cnt_all = ws + 27816;   // 120
    float* cnorm   = ws + 27936;   // 120

    hipMemsetAsync(ws, 0, 23976 * sizeof(float), stream);
    pass1_hist<<<1024, 256, 0, stream>>>(z, idx, gsum, B);
    pass2_centroids<<<1, 256, 0, stream>>>(gsum, cent, cnt_all, cnorm);
    pass3_dist<<<2048, 256, 0, stream>>>(z, idx, cent, cnorm, dsum, B);
    pass4_final<<<1, 128, 0, stream>>>(dsum, cnt_all, w, out);
}

// Round 7
// 126.206 us; speedup vs baseline: 2.7700x; 1.7047x over previous
//
#include <hip/hip_runtime.h>
#include <math.h>

// Workspace layout (floats):
//   gsum_part[8][81*33] @ 0      partial histograms: cols 0-31 = sum(z_hyp), col 32 = count
//   dsum_part[8][81*4]  @ 21384  partial per-(s4,level) distance sums
//   cent   [120*32]     @ 23976  centroids (lvl1:0-2, lvl2:3-11, lvl3:12-38, lvl4:39-119)
//   cnt_all[120]        @ 27816
//   cnorm  [120]        @ 27936  stores (1 - ||centroid||^2)
// First 23976 floats are accumulators -> memset to 0 each launch.
//
// HW notes (measured R2/R4/R5/R6):
//  - LDS atomics (ds_add_f32) are lane-serial (~5 cy/active lane) on gfx950
//    -> NEVER in hot loops. Exec-wide non-atomic b128 RMW with rank-round
//    duplicate serialization is ~10x faster.
//  - Runtime-trip scalar load loops in a 1-block kernel are latency death
//    (R6: 121 us for 120 segments) -> cooperative LDS staging first.

#define MAXR  0.95f
#define MAXR2 0.9025f
#define LN2F  0.6931471805599453f

__device__ __forceinline__ float fsqrt(float x) { return __builtin_amdgcn_sqrtf(x); }
__device__ __forceinline__ float frcp(float x)  { return __builtin_amdgcn_rcpf(x); }
__device__ __forceinline__ float frsq(float x)  { return __builtin_amdgcn_rsqf(x); }

// 8-lane sum reduction entirely in the VALU pipe via DPP:
// quad_perm xor1 = 0xB1, xor2 = 0x4E, cross-quad = row_half_mirror 0x141.
__device__ __forceinline__ float red8_dpp(float v) {
    v += __int_as_float(__builtin_amdgcn_update_dpp(0, __float_as_int(v), 0xB1, 0xF, 0xF, 1));
    v += __int_as_float(__builtin_amdgcn_update_dpp(0, __float_as_int(v), 0x4E, 0xF, 0xF, 1));
    v += __int_as_float(__builtin_amdgcn_update_dpp(0, __float_as_int(v), 0x141, 0xF, 0xF, 1));
    return v;
}

// 32-lane sum reduction: 4 DPP stages + one cross-row shuffle.
__device__ __forceinline__ float red32_dpp(float v) {
    v += __int_as_float(__builtin_amdgcn_update_dpp(0, __float_as_int(v), 0xB1, 0xF, 0xF, 1));
    v += __int_as_float(__builtin_amdgcn_update_dpp(0, __float_as_int(v), 0x4E, 0xF, 0xF, 1));
    v += __int_as_float(__builtin_amdgcn_update_dpp(0, __float_as_int(v), 0x141, 0xF, 0xF, 1));
    v += __int_as_float(__builtin_amdgcn_update_dpp(0, __float_as_int(v), 0x140, 0xF, 0xF, 1));
    v += __shfl_xor(v, 16, 32);
    return v;
}

// rank of this 8-lane group among same-s4 groups in the wave (RMW rounds).
__device__ __forceinline__ int dup_rank(int s4, int g, int sub) {
    int sj = __shfl(s4, sub * 8, 64);
    unsigned long long eq = __ballot(sj == s4);
    unsigned int row = (unsigned int)(eq >> (g * 8));
    return __popc(row & ((1u << g) - 1u));
}

// Pass 1: level-4 histogram (vector sums + counts) of projected points.
// 8 lanes/point, 4 points per wave-iter batched for ILP/MLP; DPP reductions;
// per-WAVE private LDS copy, non-atomic RMW with rank-round duplicate
// serialization. Row stride 36 floats (144 B, b128-aligned); col 32 = count.
__global__ __launch_bounds__(256) void pass1_hist(
        const float* __restrict__ z, const int* __restrict__ idx,
        float* __restrict__ gsum, int B) {
    __shared__ float lsum[4][81][36];
    const int tid = threadIdx.x;
    for (int j = tid; j < 4 * 81 * 36; j += 256) (&lsum[0][0][0])[j] = 0.f;
    __syncthreads();

    const int w = tid >> 6;
    const int g = (tid & 63) >> 3;
    const int sub = tid & 7;
    const int STRIDE = gridDim.x * 128;
    const int base0 = blockIdx.x * 128 + w * 32 + g;
    const int nfull = B / STRIDE;
    float* const lw = &lsum[w][0][0];

    for (int it = 0; it < nfull; ++it) {
        const int ib = it * STRIDE + base0;
        float4 xv[4];
        int s4v[4], rank[4];
#pragma unroll
        for (int b = 0; b < 4; ++b)
            xv[b] = *(const float4*)(z + (size_t)(ib + b * 8) * 32 + sub * 4);
#pragma unroll
        for (int b = 0; b < 4; ++b)
            s4v[b] = idx[ib + b * 8] / 243;
#pragma unroll
        for (int b = 0; b < 4; ++b) {
            const float nx = red8_dpp(xv[b].x * xv[b].x + xv[b].y * xv[b].y +
                                      xv[b].z * xv[b].z + xv[b].w * xv[b].w);
            const float s = (nx > MAXR2) ? MAXR * frsq(nx) : 1.0f;
            xv[b].x *= s; xv[b].y *= s; xv[b].z *= s; xv[b].w *= s;
        }
#pragma unroll
        for (int b = 0; b < 4; ++b)
            rank[b] = dup_rank(s4v[b], g, sub);
#pragma unroll
        for (int b = 0; b < 4; ++b) {
            float* row = lw + s4v[b] * 36;
            for (int r = 0;; ++r) {
                if (!__any(rank[b] == r)) break;
                if (rank[b] == r) {
                    float4 cur = *(float4*)(row + sub * 4);
                    cur.x += xv[b].x; cur.y += xv[b].y;
                    cur.z += xv[b].z; cur.w += xv[b].w;
                    *(float4*)(row + sub * 4) = cur;
                    if (sub == 0) row[32] += 1.0f;
                }
            }
        }
    }
    // generic tail (not executed for B = 1M with grid 1024)
    if (B % STRIDE) {
        const int ib = nfull * STRIDE + base0;
        for (int b = 0; b < 4; ++b) {
            const int i = ib + b * 8;
            const bool act = i < B;
            float4 xv = act ? *(const float4*)(z + (size_t)i * 32 + sub * 4)
                            : make_float4(0.f, 0.f, 0.f, 0.f);
            int s4 = act ? idx[i] / 243 : 81 + g;   // distinct dummy bins
            const float nx = red8_dpp(xv.x * xv.x + xv.y * xv.y +
                                      xv.z * xv.z + xv.w * xv.w);
            const float s = (nx > MAXR2) ? MAXR * frsq(nx) : 1.0f;
            xv.x *= s; xv.y *= s; xv.z *= s; xv.w *= s;
            int rank = dup_rank(s4, g, sub);
            for (int r = 0;; ++r) {
                if (!__any(rank == r)) break;
                if (act && rank == r) {
                    float* row = lw + s4 * 36;
                    float4 cur = *(float4*)(row + sub * 4);
                    cur.x += xv.x; cur.y += xv.y; cur.z += xv.z; cur.w += xv.w;
                    *(float4*)(row + sub * 4) = cur;
                    if (sub == 0) row[32] += 1.0f;
                }
            }
        }
    }
    __syncthreads();
    float* gpart = gsum + (blockIdx.x & 7) * 2673;
    for (int j = tid; j < 81 * 33; j += 256) {
        const int r = j / 33, c = j - r * 33;
        const float v = lsum[0][r][c] + lsum[1][r][c] +
                        lsum[2][r][c] + lsum[3][r][c];
        unsafeAtomicAdd(&gpart[j], v);
    }
}

// Pass 2: cooperative partial-sum into LDS -> hierarchical aggregation in
// LDS -> Frechet-mean iteration (DPP red32). 1 block, 256 threads.
// euc rows: 0-2 lvl1, 3-11 lvl2, 12-38 lvl3, 39-119 lvl4; col 32 = count.
__global__ __launch_bounds__(256) void pass2_centroids(
        const float* __restrict__ gsum,
        float* __restrict__ cent, float* __restrict__ cnt_all,
        float* __restrict__ cnorm) {
    __shared__ float euc[120][33];
    const int tid = threadIdx.x;
    // 1. sum the 8 partial histograms into level-4 rows (39..119)
    for (int j = tid; j < 2673; j += 256) {
        float s = 0.f;
#pragma unroll
        for (int p = 0; p < 8; ++p) s += gsum[p * 2673 + j];
        const int r = j / 33, c = j - r * 33;
        euc[39 + r][c] = s;
    }
    __syncthreads();
    // 2. aggregate up the hierarchy: lvl3 (12-38) <- lvl4, lvl2 <- lvl3, lvl1 <- lvl2
    for (int j = tid; j < 27 * 33; j += 256) {
        const int r = j / 33, c = j - r * 33;
        euc[12 + r][c] = euc[39 + 3 * r][c] + euc[40 + 3 * r][c] + euc[41 + 3 * r][c];
    }
    __syncthreads();
    for (int j = tid; j < 9 * 33; j += 256) {
        const int r = j / 33, c = j - r * 33;
        euc[3 + r][c] = euc[12 + 3 * r][c] + euc[13 + 3 * r][c] + euc[14 + 3 * r][c];
    }
    __syncthreads();
    for (int j = tid; j < 3 * 33; j += 256) {
        const int r = j / 33, c = j - r * 33;
        euc[r][c] = euc[3 + 3 * r][c] + euc[4 + 3 * r][c] + euc[5 + 3 * r][c];
    }
    __syncthreads();
    // 3. Frechet iteration, one 32-lane group per segment (lane = dim)
    const int lane = tid & 31;
    const int grp = tid >> 5;
    for (int t = grp; t < 120; t += 8) {
        const float sum = euc[t][lane];
        const float cnt = euc[t][32];
        const float em = sum / fmaxf(cnt, 1.0f);
        float m = em;
        {
            float norm = sqrtf(red32_dpp(m * m));
            if (norm > MAXR) m *= MAXR / (norm + 1e-12f);
        }
        for (int it = 0; it < 10; ++it) {
            float v = m + 0.1f * (em - m);
            float norm = sqrtf(red32_dpp(v * v));
            if (norm > MAXR) v *= MAXR / (norm + 1e-12f);
            m = v;
        }
        cent[t * 32 + lane] = m;
        float ny = red32_dpp(m * m);
        if (lane == 0) { cnt_all[t] = cnt; cnorm[t] = 1.0f - ny; }
    }
}

// Pass 3: per-point distances to 4 ancestor centroids, batched x4, DPP
// reductions, dot-product distance form (sq = nx+ny-2<x,c>), per-wave
// [81][4] LDS accumulator with rank-round float4 RMW (sub==0 lane).
// dl holds log2 form; ln2 applied once in pass4.
__global__ __launch_bounds__(256) void pass3_dist(
        const float* __restrict__ z, const int* __restrict__ idx,
        const float* __restrict__ cent, const float* __restrict__ cnorm,
        float* __restrict__ dsum, int B) {
    __shared__ float lcent[120 * 32];
    __shared__ float lcn[120];          // (1 - ny)
    __shared__ float ld[4][81][4];
    const int tid = threadIdx.x;
    for (int j = tid; j < 120 * 32; j += 256) lcent[j] = cent[j];
    for (int j = tid; j < 120; j += 256) lcn[j] = cnorm[j];
    for (int j = tid; j < 4 * 81 * 4; j += 256) (&ld[0][0][0])[j] = 0.f;
    __syncthreads();

    const int w = tid >> 6;
    const int g = (tid & 63) >> 3;
    const int sub = tid & 7;
    const int STRIDE = gridDim.x * 128;
    const int base0 = blockIdx.x * 128 + w * 32 + g;
    const int nfull = B / STRIDE;

    for (int it = 0; it < nfull; ++it) {
        const int ib = it * STRIDE + base0;
        float4 xv[4];
        int s4v[4], rank[4];
        float dl[4][4];
#pragma unroll
        for (int b = 0; b < 4; ++b)
            xv[b] = *(const float4*)(z + (size_t)(ib + b * 8) * 32 + sub * 4);
#pragma unroll
        for (int b = 0; b < 4; ++b)
            s4v[b] = idx[ib + b * 8] / 243;
#pragma unroll
        for (int b = 0; b < 4; ++b) {
            float nx = red8_dpp(xv[b].x * xv[b].x + xv[b].y * xv[b].y +
                                xv[b].z * xv[b].z + xv[b].w * xv[b].w);
            const float s = (nx > MAXR2) ? MAXR * frsq(nx) : 1.0f;
            xv[b].x *= s; xv[b].y *= s; xv[b].z *= s; xv[b].w *= s;
            nx = nx * s * s;
            const float ah = 0.5f * (1.0f - nx);   // (1-nx)/2
            const float c2a = 1.0f + nx;           // nx + 1
            const int s4 = s4v[b];
            const int d3 = s4 / 3, d9 = d3 / 3, d27 = d9 / 3;
            const int tl[4] = {d27, 3 + d9, 12 + d3, 39 + s4};
#pragma unroll
            for (int l = 0; l < 4; ++l) {
                const int t = tl[l];
                const float4 c = *(const float4*)(lcent + t * 32 + sub * 4);
                const float dot = red8_dpp(xv[b].x * c.x + xv[b].y * c.y +
                                           xv[b].z * c.z + xv[b].w * c.w);
                const float bny = lcn[t];
                // sq = nx + ny - 2dot = (c2a - bny) - 2dot
                const float sq = fmaf(-2.0f, dot, c2a - bny);
                const float d = fmaxf(ah * bny, 5e-13f);   // denom/2
                float tt = sq * frcp(d);
                tt = fmaxf(tt, 1e-7f);
                // acosh(1+tt) = ln(1 + tt + sqrt(tt*(tt+2)))
                dl[b][l] = __log2f(1.0f + tt + fsqrt(tt * (tt + 2.0f)));
            }
        }
#pragma unroll
        for (int b = 0; b < 4; ++b)
            rank[b] = dup_rank(s4v[b], g, sub);
#pragma unroll
        for (int b = 0; b < 4; ++b) {
            float* row = &ld[w][s4v[b]][0];
            for (int r = 0;; ++r) {
                if (!__any(rank[b] == r)) break;
                if (rank[b] == r && sub == 0) {
                    float4 cur = *(float4*)row;
                    cur.x += dl[b][0]; cur.y += dl[b][1];
                    cur.z += dl[b][2]; cur.w += dl[b][3];
                    *(float4*)row = cur;
                }
            }
        }
    }
    // generic tail (not executed for B = 1M with grid 2048)
    if (B % STRIDE) {
        const int ib = nfull * STRIDE + base0;
        for (int b = 0; b < 4; ++b) {
            const int i = ib + b * 8;
            const bool act = i < B;
            float4 xv = act ? *(const float4*)(z + (size_t)i * 32 + sub * 4)
                            : make_float4(0.f, 0.f, 0.f, 0.f);
            int s4 = act ? idx[i] / 243 : 81 + g;
            float nx = red8_dpp(xv.x * xv.x + xv.y * xv.y + xv.z * xv.z + xv.w * xv.w);
            const float s = (nx > MAXR2) ? MAXR * frsq(nx) : 1.0f;
            xv.x *= s; xv.y *= s; xv.z *= s; xv.w *= s;
            nx = nx * s * s;
            const float ah = 0.5f * (1.0f - nx);
            const float c2a = 1.0f + nx;
            const int ss = act ? s4 : 0;
            const int d3 = ss / 3, d9 = d3 / 3, d27 = d9 / 3;
            const int tl[4] = {d27, 3 + d9, 12 + d3, 39 + ss};
            float dl[4];
#pragma unroll
            for (int l = 0; l < 4; ++l) {
                const int t = tl[l];
                const float4 c = *(const float4*)(lcent + t * 32 + sub * 4);
                const float dot = red8_dpp(xv.x * c.x + xv.y * c.y +
                                           xv.z * c.z + xv.w * c.w);
                const float bny = lcn[t];
                const float sq = fmaf(-2.0f, dot, c2a - bny);
                const float d = fmaxf(ah * bny, 5e-13f);
                float tt = sq * frcp(d);
                tt = fmaxf(tt, 1e-7f);
                dl[l] = __log2f(1.0f + tt + fsqrt(tt * (tt + 2.0f)));
            }
            int rank = dup_rank(s4, g, sub);
            for (int r = 0;; ++r) {
                if (!__any(rank == r)) break;
                if (act && rank == r && sub == 0) {
                    float* row = &ld[w][s4][0];
                    float4 cur = *(float4*)row;
                    cur.x += dl[0]; cur.y += dl[1]; cur.z += dl[2]; cur.w += dl[3];
                    *(float4*)row = cur;
                }
            }
        }
    }
    __syncthreads();
    float* dpart = dsum + (blockIdx.x & 7) * 324;
    for (int j = tid; j < 81 * 4; j += 256) {
        const float v = (&ld[0][0][0])[j] + (&ld[1][0][0])[j] +
                        (&ld[2][0][0])[j] + (&ld[3][0][0])[j];
        unsafeAtomicAdd(&dpart[j], v);
    }
}

// Pass 4: finalize — aggregate per-level, apply valid/count logic + ln2,
// weighted sum.
__global__ __launch_bounds__(128) void pass4_final(
        const float* __restrict__ dsum, const float* __restrict__ cnt_all,
        const float* __restrict__ w, float* __restrict__ out) {
    __shared__ float sl[81];
    __shared__ float su[81];
    const int tid = threadIdx.x;
    const int toff[4] = {0, 3, 12, 39};
    const int nsegs[4] = {3, 9, 27, 81};
    float total = 0.f;
    for (int l = 0; l < 4; ++l) {
        const int n_seg = nsegs[l];
        const int ch = 81 / n_seg;
        __syncthreads();
        if (tid < n_seg) {
            float cnt = cnt_all[toff[l] + tid];
            float ds = 0.f;
            for (int p = 0; p < 8; ++p)
                for (int k = 0; k < ch; ++k)
                    ds += dsum[p * 324 + (tid * ch + k) * 4 + l];
            sl[tid] = (cnt >= 2.0f) ? ds * LN2F / fmaxf(cnt, 1.0f) : 0.f;
            su[tid] = (cnt > 0.0f) ? 1.f : 0.f;
        }
        __syncthreads();
        if (tid == 0) {
            float ll = 0.f, nu = 0.f;
            for (int s = 0; s < n_seg; ++s) { ll += sl[s]; nu += su[s]; }
            total += w[l] * ll / fmaxf(nu, 1.0f);
        }
    }
    if (tid == 0) out[0] = total;
}

extern "C" void kernel_launch(void* const* d_in, const int* in_sizes, int n_in,
                              void* d_out, int out_size, void* d_ws, size_t ws_size,
                              hipStream_t stream) {
    const float* z   = (const float*)d_in[0];
    const int*   idx = (const int*)d_in[1];
    const float* w   = (const float*)d_in[2];
    float* out = (float*)d_out;
    float* ws  = (float*)d_ws;
    const int B = in_sizes[1];

    float* gsum    = ws;           // 8*2673 = 21384
    float* dsum    = ws + 21384;   // 8*324  = 2592
    float* cent    = ws + 23976;   // 3840
    float* cnt_all = ws + 27816;   // 120
    float* cnorm   = ws + 27936;   // 120

    hipMemsetAsync(ws, 0, 23976 * sizeof(float), stream);
    pass1_hist<<<1024, 256, 0, stream>>>(z, idx, gsum, B);
    pass2_centroids<<<1, 256, 0, stream>>>(gsum, cent, cnt_all, cnorm);
    pass3_dist<<<2048, 256, 0, stream>>>(z, idx, cent, cnorm, dsum, B);
    pass4_final<<<1, 128, 0, stream>>>(dsum, cnt_all, w, out);
}

// Round 8
// 126.127 us; speedup vs baseline: 2.7717x; 1.0006x over previous
//
#include <hip/hip_runtime.h>
#include <math.h>

// Workspace layout (floats):
//   gsum_part[8][81*33] @ 0      partial histograms: cols 0-31 = sum(z_hyp), col 32 = count
//   dsum_part[8][81*4]  @ 21384  partial per-(s4,level) distance sums
//   cent   [120*32]     @ 23976  centroids (lvl1:0-2, lvl2:3-11, lvl3:12-38, lvl4:39-119)
//   cnt_all[120]        @ 27816
//   cnorm  [120]        @ 27936  stores (1 - ||centroid||^2)
// First 23976 floats are accumulators -> zeroed by zero_ws each launch.
//
// HW notes (measured R2/R4/R5/R6/R7):
//  - LDS atomics (ds_add_f32) are lane-serial (~5 cy/active lane) on gfx950
//    -> NEVER in hot loops. Exec-wide non-atomic b128 RMW with rank-round
//    duplicate serialization is ~10x faster.
//  - Runtime-trip scalar load loops in a 1-block kernel are latency death
//    (R6: 121 us for 120 segments) -> cooperative LDS staging first.
//  - hipMemsetAsync of a small (~100 KB) region costs ~75 us/replay
//    (rocclr fillBufferAligned slow path, R7) -> use a custom zero kernel.

#define MAXR  0.95f
#define MAXR2 0.9025f
#define LN2F  0.6931471805599453f

__device__ __forceinline__ float fsqrt(float x) { return __builtin_amdgcn_sqrtf(x); }
__device__ __forceinline__ float frcp(float x)  { return __builtin_amdgcn_rcpf(x); }
__device__ __forceinline__ float frsq(float x)  { return __builtin_amdgcn_rsqf(x); }

// 8-lane sum reduction entirely in the VALU pipe via DPP:
// quad_perm xor1 = 0xB1, xor2 = 0x4E, cross-quad = row_half_mirror 0x141.
__device__ __forceinline__ float red8_dpp(float v) {
    v += __int_as_float(__builtin_amdgcn_update_dpp(0, __float_as_int(v), 0xB1, 0xF, 0xF, 1));
    v += __int_as_float(__builtin_amdgcn_update_dpp(0, __float_as_int(v), 0x4E, 0xF, 0xF, 1));
    v += __int_as_float(__builtin_amdgcn_update_dpp(0, __float_as_int(v), 0x141, 0xF, 0xF, 1));
    return v;
}

// 32-lane sum reduction: 4 DPP stages + one cross-row shuffle.
__device__ __forceinline__ float red32_dpp(float v) {
    v += __int_as_float(__builtin_amdgcn_update_dpp(0, __float_as_int(v), 0xB1, 0xF, 0xF, 1));
    v += __int_as_float(__builtin_amdgcn_update_dpp(0, __float_as_int(v), 0x4E, 0xF, 0xF, 1));
    v += __int_as_float(__builtin_amdgcn_update_dpp(0, __float_as_int(v), 0x141, 0xF, 0xF, 1));
    v += __int_as_float(__builtin_amdgcn_update_dpp(0, __float_as_int(v), 0x140, 0xF, 0xF, 1));
    v += __shfl_xor(v, 16, 32);
    return v;
}

// rank of this 8-lane group among same-s4 groups in the wave (RMW rounds).
__device__ __forceinline__ int dup_rank(int s4, int g, int sub) {
    int sj = __shfl(s4, sub * 8, 64);
    unsigned long long eq = __ballot(sj == s4);
    unsigned int row = (unsigned int)(eq >> (g * 8));
    return __popc(row & ((1u << g) - 1u));
}

// Zero the accumulator region (23976 floats = 5994 float4s).
__global__ __launch_bounds__(256) void zero_ws(float4* __restrict__ p, int n4) {
    const int i = blockIdx.x * 256 + threadIdx.x;
    if (i < n4) p[i] = make_float4(0.f, 0.f, 0.f, 0.f);
}

// Pass 1: level-4 histogram (vector sums + counts) of projected points.
// 8 lanes/point, 4 points per wave-iter batched for ILP/MLP; DPP reductions;
// per-WAVE private LDS copy, non-atomic RMW with rank-round duplicate
// serialization. Row stride 36 floats (144 B, b128-aligned); col 32 = count.
__global__ __launch_bounds__(256) void pass1_hist(
        const float* __restrict__ z, const int* __restrict__ idx,
        float* __restrict__ gsum, int B) {
    __shared__ float lsum[4][81][36];
    const int tid = threadIdx.x;
    for (int j = tid; j < 4 * 81 * 36; j += 256) (&lsum[0][0][0])[j] = 0.f;
    __syncthreads();

    const int w = tid >> 6;
    const int g = (tid & 63) >> 3;
    const int sub = tid & 7;
    const int STRIDE = gridDim.x * 128;
    const int base0 = blockIdx.x * 128 + w * 32 + g;
    const int nfull = B / STRIDE;
    float* const lw = &lsum[w][0][0];

    for (int it = 0; it < nfull; ++it) {
        const int ib = it * STRIDE + base0;
        float4 xv[4];
        int s4v[4], rank[4];
#pragma unroll
        for (int b = 0; b < 4; ++b)
            xv[b] = *(const float4*)(z + (size_t)(ib + b * 8) * 32 + sub * 4);
#pragma unroll
        for (int b = 0; b < 4; ++b)
            s4v[b] = idx[ib + b * 8] / 243;
#pragma unroll
        for (int b = 0; b < 4; ++b) {
            const float nx = red8_dpp(xv[b].x * xv[b].x + xv[b].y * xv[b].y +
                                      xv[b].z * xv[b].z + xv[b].w * xv[b].w);
            const float s = (nx > MAXR2) ? MAXR * frsq(nx) : 1.0f;
            xv[b].x *= s; xv[b].y *= s; xv[b].z *= s; xv[b].w *= s;
        }
#pragma unroll
        for (int b = 0; b < 4; ++b)
            rank[b] = dup_rank(s4v[b], g, sub);
#pragma unroll
        for (int b = 0; b < 4; ++b) {
            float* row = lw + s4v[b] * 36;
            for (int r = 0;; ++r) {
                if (!__any(rank[b] == r)) break;
                if (rank[b] == r) {
                    float4 cur = *(float4*)(row + sub * 4);
                    cur.x += xv[b].x; cur.y += xv[b].y;
                    cur.z += xv[b].z; cur.w += xv[b].w;
                    *(float4*)(row + sub * 4) = cur;
                    if (sub == 0) row[32] += 1.0f;
                }
            }
        }
    }
    // generic tail (not executed for B = 1M with grid 1024)
    if (B % STRIDE) {
        const int ib = nfull * STRIDE + base0;
        for (int b = 0; b < 4; ++b) {
            const int i = ib + b * 8;
            const bool act = i < B;
            float4 xv = act ? *(const float4*)(z + (size_t)i * 32 + sub * 4)
                            : make_float4(0.f, 0.f, 0.f, 0.f);
            int s4 = act ? idx[i] / 243 : 81 + g;   // distinct dummy bins
            const float nx = red8_dpp(xv.x * xv.x + xv.y * xv.y +
                                      xv.z * xv.z + xv.w * xv.w);
            const float s = (nx > MAXR2) ? MAXR * frsq(nx) : 1.0f;
            xv.x *= s; xv.y *= s; xv.z *= s; xv.w *= s;
            int rank = dup_rank(s4, g, sub);
            for (int r = 0;; ++r) {
                if (!__any(rank == r)) break;
                if (act && rank == r) {
                    float* row = lw + s4 * 36;
                    float4 cur = *(float4*)(row + sub * 4);
                    cur.x += xv.x; cur.y += xv.y; cur.z += xv.z; cur.w += xv.w;
                    *(float4*)(row + sub * 4) = cur;
                    if (sub == 0) row[32] += 1.0f;
                }
            }
        }
    }
    __syncthreads();
    float* gpart = gsum + (blockIdx.x & 7) * 2673;
    for (int j = tid; j < 81 * 33; j += 256) {
        const int r = j / 33, c = j - r * 33;
        const float v = lsum[0][r][c] + lsum[1][r][c] +
                        lsum[2][r][c] + lsum[3][r][c];
        unsafeAtomicAdd(&gpart[j], v);
    }
}

// Pass 2: cooperative partial-sum into LDS -> hierarchical aggregation in
// LDS -> Frechet-mean iteration (DPP red32). 1 block, 256 threads.
// euc rows: 0-2 lvl1, 3-11 lvl2, 12-38 lvl3, 39-119 lvl4; col 32 = count.
__global__ __launch_bounds__(256) void pass2_centroids(
        const float* __restrict__ gsum,
        float* __restrict__ cent, float* __restrict__ cnt_all,
        float* __restrict__ cnorm) {
    __shared__ float euc[120][33];
    const int tid = threadIdx.x;
    // 1. sum the 8 partial histograms into level-4 rows (39..119)
    for (int j = tid; j < 2673; j += 256) {
        float s = 0.f;
#pragma unroll
        for (int p = 0; p < 8; ++p) s += gsum[p * 2673 + j];
        const int r = j / 33, c = j - r * 33;
        euc[39 + r][c] = s;
    }
    __syncthreads();
    // 2. aggregate up the hierarchy
    for (int j = tid; j < 27 * 33; j += 256) {
        const int r = j / 33, c = j - r * 33;
        euc[12 + r][c] = euc[39 + 3 * r][c] + euc[40 + 3 * r][c] + euc[41 + 3 * r][c];
    }
    __syncthreads();
    for (int j = tid; j < 9 * 33; j += 256) {
        const int r = j / 33, c = j - r * 33;
        euc[3 + r][c] = euc[12 + 3 * r][c] + euc[13 + 3 * r][c] + euc[14 + 3 * r][c];
    }
    __syncthreads();
    for (int j = tid; j < 3 * 33; j += 256) {
        const int r = j / 33, c = j - r * 33;
        euc[r][c] = euc[3 + 3 * r][c] + euc[4 + 3 * r][c] + euc[5 + 3 * r][c];
    }
    __syncthreads();
    // 3. Frechet iteration, one 32-lane group per segment (lane = dim)
    const int lane = tid & 31;
    const int grp = tid >> 5;
    for (int t = grp; t < 120; t += 8) {
        const float sum = euc[t][lane];
        const float cnt = euc[t][32];
        const float em = sum / fmaxf(cnt, 1.0f);
        float m = em;
        {
            float norm = sqrtf(red32_dpp(m * m));
            if (norm > MAXR) m *= MAXR / (norm + 1e-12f);
        }
        for (int it = 0; it < 10; ++it) {
            float v = m + 0.1f * (em - m);
            float norm = sqrtf(red32_dpp(v * v));
            if (norm > MAXR) v *= MAXR / (norm + 1e-12f);
            m = v;
        }
        cent[t * 32 + lane] = m;
        float ny = red32_dpp(m * m);
        if (lane == 0) { cnt_all[t] = cnt; cnorm[t] = 1.0f - ny; }
    }
}

// Pass 3: per-point distances to 4 ancestor centroids, batched x4, DPP
// reductions, dot-product distance form (sq = nx+ny-2<x,c>), per-wave
// [81][4] LDS accumulator with rank-round float4 RMW (sub==0 lane).
// dl holds log2 form; ln2 applied once in pass4.
__global__ __launch_bounds__(256) void pass3_dist(
        const float* __restrict__ z, const int* __restrict__ idx,
        const float* __restrict__ cent, const float* __restrict__ cnorm,
        float* __restrict__ dsum, int B) {
    __shared__ float lcent[120 * 32];
    __shared__ float lcn[120];          // (1 - ny)
    __shared__ float ld[4][81][4];
    const int tid = threadIdx.x;
    for (int j = tid; j < 120 * 32; j += 256) lcent[j] = cent[j];
    for (int j = tid; j < 120; j += 256) lcn[j] = cnorm[j];
    for (int j = tid; j < 4 * 81 * 4; j += 256) (&ld[0][0][0])[j] = 0.f;
    __syncthreads();

    const int w = tid >> 6;
    const int g = (tid & 63) >> 3;
    const int sub = tid & 7;
    const int STRIDE = gridDim.x * 128;
    const int base0 = blockIdx.x * 128 + w * 32 + g;
    const int nfull = B / STRIDE;

    for (int it = 0; it < nfull; ++it) {
        const int ib = it * STRIDE + base0;
        float4 xv[4];
        int s4v[4], rank[4];
        float dl[4][4];
#pragma unroll
        for (int b = 0; b < 4; ++b)
            xv[b] = *(const float4*)(z + (size_t)(ib + b * 8) * 32 + sub * 4);
#pragma unroll
        for (int b = 0; b < 4; ++b)
            s4v[b] = idx[ib + b * 8] / 243;
#pragma unroll
        for (int b = 0; b < 4; ++b) {
            float nx = red8_dpp(xv[b].x * xv[b].x + xv[b].y * xv[b].y +
                                xv[b].z * xv[b].z + xv[b].w * xv[b].w);
            const float s = (nx > MAXR2) ? MAXR * frsq(nx) : 1.0f;
            xv[b].x *= s; xv[b].y *= s; xv[b].z *= s; xv[b].w *= s;
            nx = nx * s * s;
            const float ah = 0.5f * (1.0f - nx);   // (1-nx)/2
            const float c2a = 1.0f + nx;           // nx + 1
            const int s4 = s4v[b];
            const int d3 = s4 / 3, d9 = d3 / 3, d27 = d9 / 3;
            const int tl[4] = {d27, 3 + d9, 12 + d3, 39 + s4};
#pragma unroll
            for (int l = 0; l < 4; ++l) {
                const int t = tl[l];
                const float4 c = *(const float4*)(lcent + t * 32 + sub * 4);
                const float dot = red8_dpp(xv[b].x * c.x + xv[b].y * c.y +
                                           xv[b].z * c.z + xv[b].w * c.w);
                const float bny = lcn[t];
                // sq = nx + ny - 2dot = (c2a - bny) - 2dot
                const float sq = fmaf(-2.0f, dot, c2a - bny);
                const float d = fmaxf(ah * bny, 5e-13f);   // denom/2
                float tt = sq * frcp(d);
                tt = fmaxf(tt, 1e-7f);
                // acosh(1+tt) = ln(1 + tt + sqrt(tt*(tt+2)))
                dl[b][l] = __log2f(1.0f + tt + fsqrt(tt * (tt + 2.0f)));
            }
        }
#pragma unroll
        for (int b = 0; b < 4; ++b)
            rank[b] = dup_rank(s4v[b], g, sub);
#pragma unroll
        for (int b = 0; b < 4; ++b) {
            float* row = &ld[w][s4v[b]][0];
            for (int r = 0;; ++r) {
                if (!__any(rank[b] == r)) break;
                if (rank[b] == r && sub == 0) {
                    float4 cur = *(float4*)row;
                    cur.x += dl[b][0]; cur.y += dl[b][1];
                    cur.z += dl[b][2]; cur.w += dl[b][3];
                    *(float4*)row = cur;
                }
            }
        }
    }
    // generic tail (not executed for B = 1M with grid 2048)
    if (B % STRIDE) {
        const int ib = nfull * STRIDE + base0;
        for (int b = 0; b < 4; ++b) {
            const int i = ib + b * 8;
            const bool act = i < B;
            float4 xv = act ? *(const float4*)(z + (size_t)i * 32 + sub * 4)
                            : make_float4(0.f, 0.f, 0.f, 0.f);
            int s4 = act ? idx[i] / 243 : 81 + g;
            float nx = red8_dpp(xv.x * xv.x + xv.y * xv.y + xv.z * xv.z + xv.w * xv.w);
            const float s = (nx > MAXR2) ? MAXR * frsq(nx) : 1.0f;
            xv.x *= s; xv.y *= s; xv.z *= s; xv.w *= s;
            nx = nx * s * s;
            const float ah = 0.5f * (1.0f - nx);
            const float c2a = 1.0f + nx;
            const int ss = act ? s4 : 0;
            const int d3 = ss / 3, d9 = d3 / 3, d27 = d9 / 3;
            const int tl[4] = {d27, 3 + d9, 12 + d3, 39 + ss};
            float dl[4];
#pragma unroll
            for (int l = 0; l < 4; ++l) {
                const int t = tl[l];
                const float4 c = *(const float4*)(lcent + t * 32 + sub * 4);
                const float dot = red8_dpp(xv.x * c.x + xv.y * c.y +
                                           xv.z * c.z + xv.w * c.w);
                const float bny = lcn[t];
                const float sq = fmaf(-2.0f, dot, c2a - bny);
                const float d = fmaxf(ah * bny, 5e-13f);
                float tt = sq * frcp(d);
                tt = fmaxf(tt, 1e-7f);
                dl[l] = __log2f(1.0f + tt + fsqrt(tt * (tt + 2.0f)));
            }
            int rank = dup_rank(s4, g, sub);
            for (int r = 0;; ++r) {
                if (!__any(rank == r)) break;
                if (act && rank == r && sub == 0) {
                    float* row = &ld[w][s4][0];
                    float4 cur = *(float4*)row;
                    cur.x += dl[0]; cur.y += dl[1]; cur.z += dl[2]; cur.w += dl[3];
                    *(float4*)row = cur;
                }
            }
        }
    }
    __syncthreads();
    float* dpart = dsum + (blockIdx.x & 7) * 324;
    for (int j = tid; j < 81 * 4; j += 256) {
        const float v = (&ld[0][0][0])[j] + (&ld[1][0][0])[j] +
                        (&ld[2][0][0])[j] + (&ld[3][0][0])[j];
        unsafeAtomicAdd(&dpart[j], v);
    }
}

// Pass 4: finalize — aggregate per-level, apply valid/count logic + ln2,
// weighted sum.
__global__ __launch_bounds__(128) void pass4_final(
        const float* __restrict__ dsum, const float* __restrict__ cnt_all,
        const float* __restrict__ w, float* __restrict__ out) {
    __shared__ float sl[81];
    __shared__ float su[81];
    const int tid = threadIdx.x;
    const int toff[4] = {0, 3, 12, 39};
    const int nsegs[4] = {3, 9, 27, 81};
    float total = 0.f;
    for (int l = 0; l < 4; ++l) {
        const int n_seg = nsegs[l];
        const int ch = 81 / n_seg;
        __syncthreads();
        if (tid < n_seg) {
            float cnt = cnt_all[toff[l] + tid];
            float ds = 0.f;
            for (int p = 0; p < 8; ++p)
                for (int k = 0; k < ch; ++k)
                    ds += dsum[p * 324 + (tid * ch + k) * 4 + l];
            sl[tid] = (cnt >= 2.0f) ? ds * LN2F / fmaxf(cnt, 1.0f) : 0.f;
            su[tid] = (cnt > 0.0f) ? 1.f : 0.f;
        }
        __syncthreads();
        if (tid == 0) {
            float ll = 0.f, nu = 0.f;
            for (int s = 0; s < n_seg; ++s) { ll += sl[s]; nu += su[s]; }
            total += w[l] * ll / fmaxf(nu, 1.0f);
        }
    }
    if (tid == 0) out[0] = total;
}

extern "C" void kernel_launch(void* const* d_in, const int* in_sizes, int n_in,
                              void* d_out, int out_size, void* d_ws, size_t ws_size,
                              hipStream_t stream) {
    const float* z   = (const float*)d_in[0];
    const int*   idx = (const int*)d_in[1];
    const float* w   = (const float*)d_in[2];
    float* out = (float*)d_out;
    float* ws  = (float*)d_ws;
    const int B = in_sizes[1];

    float* gsum    = ws;           // 8*2673 = 21384
    float* dsum    = ws + 21384;   // 8*324  = 2592
    float* cent    = ws + 23976;   // 3840
    float* cnt_all = ws + 27816;   // 120
    float* cnorm   = ws + 27936;   // 120

    zero_ws<<<24, 256, 0, stream>>>((float4*)ws, 5994);   // 23976 floats
    pass1_hist<<<1024, 256, 0, stream>>>(z, idx, gsum, B);
    pass2_centroids<<<1, 256, 0, stream>>>(gsum, cent, cnt_all, cnorm);
    pass3_dist<<<2048, 256, 0, stream>>>(z, idx, cent, cnorm, dsum, B);
    pass4_final<<<1, 128, 0, stream>>>(dsum, cnt_all, w, out);
}

// Round 9
// 122.750 us; speedup vs baseline: 2.8480x; 1.0275x over previous
//
#include <hip/hip_runtime.h>
#include <math.h>

// Workspace layout (floats):
//   part  [1024][2673] @ 0        per-block histograms (cols 0-31 sum, col 32 count)
//   hsum8 [8][2673]    @ 2737152  stage-2 partial histograms
//   dsum  [8][324]     @ 2758536  partial per-(s4,level) distance sums
//   cent  [120*32]     @ 2761128  centroids (lvl1:0-2, lvl2:3-11, lvl3:12-38, lvl4:39-119)
//   cnt_all[120]       @ 2764968
//   cnorm4[81*4]       @ 2765088  float4 per s4: (1-||c||^2) of the 4 ancestors
//   tidx4 [81*4]       @ 2765412  int4  per s4: centroid ids of the 4 ancestors
// part/hsum8/cent/... are fully overwritten each launch; dsum zeroed by pass2a.
//
// HW notes (measured R2/R4/R5/R6/R7/R8):
//  - LDS atomics (ds_add_f32) are lane-serial (~5 cy/active lane) -> never in
//    hot loops; exec-wide non-atomic b128 RMW + rank-round dup serialization.
//  - Runtime-trip scalar load loops in a 1-block kernel are latency death.
//  - Global f32 atomics in flush paths scale with blocks x bins -> plain
//    stores to per-block slices + hierarchical reduction kernel.

#define MAXR  0.95f
#define MAXR2 0.9025f
#define LN2F  0.6931471805599453f

#define NPART 1024
#define HCOLS 2673              // 81*33
#define OFF_HSUM8 (NPART * HCOLS)           // 2737152
#define OFF_DSUM  (OFF_HSUM8 + 8 * HCOLS)   // 2758536
#define OFF_CENT  (OFF_DSUM + 8 * 324)      // 2761128
#define OFF_CNT   (OFF_CENT + 120 * 32)     // 2764968
#define OFF_CN4   (OFF_CNT + 120)           // 2765088
#define OFF_TI4   (OFF_CN4 + 324)           // 2765412

__device__ __forceinline__ float fsqrt(float x) { return __builtin_amdgcn_sqrtf(x); }
__device__ __forceinline__ float frcp(float x)  { return __builtin_amdgcn_rcpf(x); }
__device__ __forceinline__ float frsq(float x)  { return __builtin_amdgcn_rsqf(x); }

// 8-lane sum reduction in the VALU pipe via DPP.
__device__ __forceinline__ float red8_dpp(float v) {
    v += __int_as_float(__builtin_amdgcn_update_dpp(0, __float_as_int(v), 0xB1, 0xF, 0xF, 1));
    v += __int_as_float(__builtin_amdgcn_update_dpp(0, __float_as_int(v), 0x4E, 0xF, 0xF, 1));
    v += __int_as_float(__builtin_amdgcn_update_dpp(0, __float_as_int(v), 0x141, 0xF, 0xF, 1));
    return v;
}

// 32-lane sum reduction: 4 DPP stages + one cross-row shuffle.
__device__ __forceinline__ float red32_dpp(float v) {
    v += __int_as_float(__builtin_amdgcn_update_dpp(0, __float_as_int(v), 0xB1, 0xF, 0xF, 1));
    v += __int_as_float(__builtin_amdgcn_update_dpp(0, __float_as_int(v), 0x4E, 0xF, 0xF, 1));
    v += __int_as_float(__builtin_amdgcn_update_dpp(0, __float_as_int(v), 0x141, 0xF, 0xF, 1));
    v += __int_as_float(__builtin_amdgcn_update_dpp(0, __float_as_int(v), 0x140, 0xF, 0xF, 1));
    v += __shfl_xor(v, 16, 32);
    return v;
}

// rank of this 8-lane group among same-s4 groups in the wave (RMW rounds).
__device__ __forceinline__ int dup_rank(int s4, int g, int sub) {
    int sj = __shfl(s4, sub * 8, 64);
    unsigned long long eq = __ballot(sj == s4);
    unsigned int row = (unsigned int)(eq >> (g * 8));
    return __popc(row & ((1u << g) - 1u));
}

// Pass 1: level-4 histogram (vector sums + counts) of projected points.
// 8 lanes/point, 4 points per wave-iter batched; DPP reductions; per-WAVE
// private LDS copy, non-atomic b128 RMW with rank-round dup serialization.
// Flush: plain stores to this block's own partial slice (NO atomics).
__global__ __launch_bounds__(256) void pass1_hist(
        const float* __restrict__ z, const int* __restrict__ idx,
        float* __restrict__ part, int B) {
    __shared__ float lsum[4][81][36];
    const int tid = threadIdx.x;
    for (int j = tid; j < 4 * 81 * 36; j += 256) (&lsum[0][0][0])[j] = 0.f;
    __syncthreads();

    const int w = tid >> 6;
    const int g = (tid & 63) >> 3;
    const int sub = tid & 7;
    const int STRIDE = gridDim.x * 128;
    const int base0 = blockIdx.x * 128 + w * 32 + g;
    const int nfull = B / STRIDE;
    float* const lw = &lsum[w][0][0];

    for (int it = 0; it < nfull; ++it) {
        const int ib = it * STRIDE + base0;
        float4 xv[4];
        int s4v[4], rank[4];
#pragma unroll
        for (int b = 0; b < 4; ++b)
            xv[b] = *(const float4*)(z + (size_t)(ib + b * 8) * 32 + sub * 4);
#pragma unroll
        for (int b = 0; b < 4; ++b)
            s4v[b] = idx[ib + b * 8] / 243;
#pragma unroll
        for (int b = 0; b < 4; ++b) {
            const float nx = red8_dpp(xv[b].x * xv[b].x + xv[b].y * xv[b].y +
                                      xv[b].z * xv[b].z + xv[b].w * xv[b].w);
            const float s = (nx > MAXR2) ? MAXR * frsq(nx) : 1.0f;
            xv[b].x *= s; xv[b].y *= s; xv[b].z *= s; xv[b].w *= s;
        }
#pragma unroll
        for (int b = 0; b < 4; ++b)
            rank[b] = dup_rank(s4v[b], g, sub);
#pragma unroll
        for (int b = 0; b < 4; ++b) {
            float* row = lw + s4v[b] * 36;
            for (int r = 0;; ++r) {
                if (!__any(rank[b] == r)) break;
                if (rank[b] == r) {
                    float4 cur = *(float4*)(row + sub * 4);
                    cur.x += xv[b].x; cur.y += xv[b].y;
                    cur.z += xv[b].z; cur.w += xv[b].w;
                    *(float4*)(row + sub * 4) = cur;
                    if (sub == 0) row[32] += 1.0f;
                }
            }
        }
    }
    // generic tail (not executed for B = 1M with grid 1024: 8 exact iters)
    if (B % STRIDE) {
        const int ib = nfull * STRIDE + base0;
        for (int b = 0; b < 4; ++b) {
            const int i = ib + b * 8;
            const bool act = i < B;
            float4 xv = act ? *(const float4*)(z + (size_t)i * 32 + sub * 4)
                            : make_float4(0.f, 0.f, 0.f, 0.f);
            int s4 = act ? idx[i] / 243 : 81 + g;
            const float nx = red8_dpp(xv.x * xv.x + xv.y * xv.y +
                                      xv.z * xv.z + xv.w * xv.w);
            const float s = (nx > MAXR2) ? MAXR * frsq(nx) : 1.0f;
            xv.x *= s; xv.y *= s; xv.z *= s; xv.w *= s;
            int rank = dup_rank(s4, g, sub);
            for (int r = 0;; ++r) {
                if (!__any(rank == r)) break;
                if (act && rank == r) {
                    float* row = lw + s4 * 36;
                    float4 cur = *(float4*)(row + sub * 4);
                    cur.x += xv.x; cur.y += xv.y; cur.z += xv.z; cur.w += xv.w;
                    *(float4*)(row + sub * 4) = cur;
                    if (sub == 0) row[32] += 1.0f;
                }
            }
        }
    }
    __syncthreads();
    float* myslice = part + (size_t)blockIdx.x * HCOLS;
    for (int j = tid; j < HCOLS; j += 256) {
        const int r = j / 33, c = j - r * 33;
        myslice[j] = lsum[0][r][c] + lsum[1][r][c] +
                     lsum[2][r][c] + lsum[3][r][c];
    }
}

// Pass 2a: reduce 1024 partial histograms -> 8. Grid 88 blocks:
// group = bi/11 (which 128-slice of partials), jb = bi%11 (column chunk).
// Block 0 additionally zeroes the dsum accumulators.
__global__ __launch_bounds__(256) void pass2a_reduce(
        const float* __restrict__ part, float* __restrict__ hsum8,
        float* __restrict__ dsum) {
    const int tid = threadIdx.x;
    const int group = blockIdx.x / 11;
    const int jb = blockIdx.x - group * 11;
    const int j = jb * 256 + tid;
    if (blockIdx.x == 0)
        for (int k = tid; k < 8 * 324; k += 256) dsum[k] = 0.f;
    if (j < HCOLS) {
        const float* p0 = part + (size_t)(group * 128) * HCOLS + j;
        float s0 = 0.f, s1 = 0.f, s2 = 0.f, s3 = 0.f;
        for (int b = 0; b < 128; b += 4) {
            s0 += p0[(size_t)b * HCOLS];
            s1 += p0[(size_t)(b + 1) * HCOLS];
            s2 += p0[(size_t)(b + 2) * HCOLS];
            s3 += p0[(size_t)(b + 3) * HCOLS];
        }
        hsum8[group * HCOLS + j] = (s0 + s1) + (s2 + s3);
    }
}

// Pass 2: cooperative partial-sum into LDS -> hierarchical aggregation ->
// Frechet-mean iteration (DPP red32) -> emit cent, cnt_all, and per-s4
// ancestor tables (tidx4 int4, cnorm4 float4).
__global__ __launch_bounds__(256) void pass2_centroids(
        const float* __restrict__ hsum8,
        float* __restrict__ cent, float* __restrict__ cnt_all,
        float* __restrict__ cnorm4, int* __restrict__ tidx4) {
    __shared__ float euc[120][33];
    __shared__ float cn[120];
    const int tid = threadIdx.x;
    // 1. sum the 8 partial histograms into level-4 rows (39..119)
    for (int j = tid; j < HCOLS; j += 256) {
        float s = 0.f;
#pragma unroll
        for (int p = 0; p < 8; ++p) s += hsum8[p * HCOLS + j];
        const int r = j / 33, c = j - r * 33;
        euc[39 + r][c] = s;
    }
    __syncthreads();
    // 2. aggregate up the hierarchy
    for (int j = tid; j < 27 * 33; j += 256) {
        const int r = j / 33, c = j - r * 33;
        euc[12 + r][c] = euc[39 + 3 * r][c] + euc[40 + 3 * r][c] + euc[41 + 3 * r][c];
    }
    __syncthreads();
    for (int j = tid; j < 9 * 33; j += 256) {
        const int r = j / 33, c = j - r * 33;
        euc[3 + r][c] = euc[12 + 3 * r][c] + euc[13 + 3 * r][c] + euc[14 + 3 * r][c];
    }
    __syncthreads();
    for (int j = tid; j < 3 * 33; j += 256) {
        const int r = j / 33, c = j - r * 33;
        euc[r][c] = euc[3 + 3 * r][c] + euc[4 + 3 * r][c] + euc[5 + 3 * r][c];
    }
    __syncthreads();
    // 3. Frechet iteration, one 32-lane group per segment (lane = dim)
    const int lane = tid & 31;
    const int grp = tid >> 5;
    for (int t = grp; t < 120; t += 8) {
        const float sum = euc[t][lane];
        const float cnt = euc[t][32];
        const float em = sum / fmaxf(cnt, 1.0f);
        float m = em;
        {
            float norm = sqrtf(red32_dpp(m * m));
            if (norm > MAXR) m *= MAXR / (norm + 1e-12f);
        }
        for (int it = 0; it < 10; ++it) {
            float v = m + 0.1f * (em - m);
            float norm = sqrtf(red32_dpp(v * v));
            if (norm > MAXR) v *= MAXR / (norm + 1e-12f);
            m = v;
        }
        cent[t * 32 + lane] = m;
        float ny = red32_dpp(m * m);
        if (lane == 0) { cnt_all[t] = cnt; cn[t] = 1.0f - ny; }
    }
    __syncthreads();
    // 4. per-s4 ancestor tables
    if (tid < 81) {
        const int s4 = tid;
        const int d3 = s4 / 3, d9 = d3 / 3, d27 = d9 / 3;
        const int t0 = d27, t1 = 3 + d9, t2 = 12 + d3, t3 = 39 + s4;
        ((int4*)tidx4)[s4] = make_int4(t0, t1, t2, t3);
        ((float4*)cnorm4)[s4] = make_float4(cn[t0], cn[t1], cn[t2], cn[t3]);
    }
}

// Pass 3: per-point distances to 4 ancestor centroids, batched x4, DPP
// reductions, dot-product distance form (sq = nx+ny-2<x,c>), ancestor
// ids/norms via single b128 LDS reads, per-wave [81][4] LDS accumulator
// with rank-round float4 RMW. dl in log2 form; ln2 applied in pass4.
__global__ __launch_bounds__(256) void pass3_dist(
        const float* __restrict__ z, const int* __restrict__ idx,
        const float* __restrict__ cent, const float* __restrict__ cnorm4,
        const int* __restrict__ tidx4, float* __restrict__ dsum, int B) {
    __shared__ float lcent[120 * 32];
    __shared__ float4 lcn4[81];
    __shared__ int4 ltl4[81];
    __shared__ float ld[4][81][4];
    const int tid = threadIdx.x;
    for (int j = tid; j < 120 * 32; j += 256) lcent[j] = cent[j];
    for (int j = tid; j < 324; j += 256) ((float*)lcn4)[j] = cnorm4[j];
    for (int j = tid; j < 324; j += 256) ((int*)ltl4)[j] = tidx4[j];
    for (int j = tid; j < 4 * 81 * 4; j += 256) (&ld[0][0][0])[j] = 0.f;
    __syncthreads();

    const int w = tid >> 6;
    const int g = (tid & 63) >> 3;
    const int sub = tid & 7;
    const int STRIDE = gridDim.x * 128;
    const int base0 = blockIdx.x * 128 + w * 32 + g;
    const int nfull = B / STRIDE;

    for (int it = 0; it < nfull; ++it) {
        const int ib = it * STRIDE + base0;
        float4 xv[4];
        int s4v[4], rank[4];
        float dl[4][4];
#pragma unroll
        for (int b = 0; b < 4; ++b)
            xv[b] = *(const float4*)(z + (size_t)(ib + b * 8) * 32 + sub * 4);
#pragma unroll
        for (int b = 0; b < 4; ++b)
            s4v[b] = idx[ib + b * 8] / 243;
#pragma unroll
        for (int b = 0; b < 4; ++b) {
            float nx = red8_dpp(xv[b].x * xv[b].x + xv[b].y * xv[b].y +
                                xv[b].z * xv[b].z + xv[b].w * xv[b].w);
            const float s = (nx > MAXR2) ? MAXR * frsq(nx) : 1.0f;
            xv[b].x *= s; xv[b].y *= s; xv[b].z *= s; xv[b].w *= s;
            nx = nx * s * s;
            const float ah = 0.5f * (1.0f - nx);   // (1-nx)/2
            const float c2a = 1.0f + nx;
            const int s4 = s4v[b];
            const int4 t4 = ltl4[s4];
            const float4 cn4 = lcn4[s4];
            const int tls[4] = {t4.x, t4.y, t4.z, t4.w};
            const float bnys[4] = {cn4.x, cn4.y, cn4.z, cn4.w};
#pragma unroll
            for (int l = 0; l < 4; ++l) {
                const int t = tls[l];
                const float4 c = *(const float4*)(lcent + t * 32 + sub * 4);
                const float dot = red8_dpp(xv[b].x * c.x + xv[b].y * c.y +
                                           xv[b].z * c.z + xv[b].w * c.w);
                const float bny = bnys[l];
                const float sq = fmaf(-2.0f, dot, c2a - bny);
                const float d = fmaxf(ah * bny, 5e-13f);   // denom/2
                float tt = sq * frcp(d);
                tt = fmaxf(tt, 1e-7f);
                // acosh(1+tt) = ln(1 + tt + sqrt(tt*(tt+2)))
                dl[b][l] = __log2f(1.0f + tt + fsqrt(tt * (tt + 2.0f)));
            }
        }
#pragma unroll
        for (int b = 0; b < 4; ++b)
            rank[b] = dup_rank(s4v[b], g, sub);
#pragma unroll
        for (int b = 0; b < 4; ++b) {
            float* row = &ld[w][s4v[b]][0];
            for (int r = 0;; ++r) {
                if (!__any(rank[b] == r)) break;
                if (rank[b] == r && sub == 0) {
                    float4 cur = *(float4*)row;
                    cur.x += dl[b][0]; cur.y += dl[b][1];
                    cur.z += dl[b][2]; cur.w += dl[b][3];
                    *(float4*)row = cur;
                }
            }
        }
    }
    // generic tail (not executed for B = 1M with grid 2048: 4 exact iters)
    if (B % STRIDE) {
        const int ib = nfull * STRIDE + base0;
        for (int b = 0; b < 4; ++b) {
            const int i = ib + b * 8;
            const bool act = i < B;
            float4 xv = act ? *(const float4*)(z + (size_t)i * 32 + sub * 4)
                            : make_float4(0.f, 0.f, 0.f, 0.f);
            int s4 = act ? idx[i] / 243 : 81 + g;
            float nx = red8_dpp(xv.x * xv.x + xv.y * xv.y + xv.z * xv.z + xv.w * xv.w);
            const float s = (nx > MAXR2) ? MAXR * frsq(nx) : 1.0f;
            xv.x *= s; xv.y *= s; xv.z *= s; xv.w *= s;
            nx = nx * s * s;
            const float ah = 0.5f * (1.0f - nx);
            const float c2a = 1.0f + nx;
            const int ss = act ? s4 : 0;
            const int4 t4 = ltl4[ss];
            const float4 cn4 = lcn4[ss];
            const int tls[4] = {t4.x, t4.y, t4.z, t4.w};
            const float bnys[4] = {cn4.x, cn4.y, cn4.z, cn4.w};
            float dl[4];
#pragma unroll
            for (int l = 0; l < 4; ++l) {
                const int t = tls[l];
                const float4 c = *(const float4*)(lcent + t * 32 + sub * 4);
                const float dot = red8_dpp(xv.x * c.x + xv.y * c.y +
                                           xv.z * c.z + xv.w * c.w);
                const float bny = bnys[l];
                const float sq = fmaf(-2.0f, dot, c2a - bny);
                const float d = fmaxf(ah * bny, 5e-13f);
                float tt = sq * frcp(d);
                tt = fmaxf(tt, 1e-7f);
                dl[l] = __log2f(1.0f + tt + fsqrt(tt * (tt + 2.0f)));
            }
            int rank = dup_rank(s4, g, sub);
            for (int r = 0;; ++r) {
                if (!__any(rank == r)) break;
                if (act && rank == r && sub == 0) {
                    float* row = &ld[w][s4][0];
                    float4 cur = *(float4*)row;
                    cur.x += dl[0]; cur.y += dl[1]; cur.z += dl[2]; cur.w += dl[3];
                    *(float4*)row = cur;
                }
            }
        }
    }
    __syncthreads();
    float* dpart = dsum + (blockIdx.x & 7) * 324;
    for (int j = tid; j < 81 * 4; j += 256) {
        const float v = (&ld[0][0][0])[j] + (&ld[1][0][0])[j] +
                        (&ld[2][0][0])[j] + (&ld[3][0][0])[j];
        unsafeAtomicAdd(&dpart[j], v);
    }
}

// Pass 4: finalize — aggregate per-level, apply valid/count logic + ln2,
// weighted sum.
__global__ __launch_bounds__(128) void pass4_final(
        const float* __restrict__ dsum, const float* __restrict__ cnt_all,
        const float* __restrict__ w, float* __restrict__ out) {
    __shared__ float sl[81];
    __shared__ float su[81];
    const int tid = threadIdx.x;
    const int toff[4] = {0, 3, 12, 39};
    const int nsegs[4] = {3, 9, 27, 81};
    float total = 0.f;
    for (int l = 0; l < 4; ++l) {
        const int n_seg = nsegs[l];
        const int ch = 81 / n_seg;
        __syncthreads();
        if (tid < n_seg) {
            float cnt = cnt_all[toff[l] + tid];
            float ds = 0.f;
            for (int p = 0; p < 8; ++p)
                for (int k = 0; k < ch; ++k)
                    ds += dsum[p * 324 + (tid * ch + k) * 4 + l];
            sl[tid] = (cnt >= 2.0f) ? ds * LN2F / fmaxf(cnt, 1.0f) : 0.f;
            su[tid] = (cnt > 0.0f) ? 1.f : 0.f;
        }
        __syncthreads();
        if (tid == 0) {
            float ll = 0.f, nu = 0.f;
            for (int s = 0; s < n_seg; ++s) { ll += sl[s]; nu += su[s]; }
            total += w[l] * ll / fmaxf(nu, 1.0f);
        }
    }
    if (tid == 0) out[0] = total;
}

extern "C" void kernel_launch(void* const* d_in, const int* in_sizes, int n_in,
                              void* d_out, int out_size, void* d_ws, size_t ws_size,
                              hipStream_t stream) {
    const float* z   = (const float*)d_in[0];
    const int*   idx = (const int*)d_in[1];
    const float* w   = (const float*)d_in[2];
    float* out = (float*)d_out;
    float* ws  = (float*)d_ws;
    const int B = in_sizes[1];

    float* part    = ws;
    float* hsum8   = ws + OFF_HSUM8;
    float* dsum    = ws + OFF_DSUM;
    float* cent    = ws + OFF_CENT;
    float* cnt_all = ws + OFF_CNT;
    float* cnorm4  = ws + OFF_CN4;
    int*   tidx4   = (int*)(ws + OFF_TI4);

    pass1_hist<<<NPART, 256, 0, stream>>>(z, idx, part, B);
    pass2a_reduce<<<88, 256, 0, stream>>>(part, hsum8, dsum);
    pass2_centroids<<<1, 256, 0, stream>>>(hsum8, cent, cnt_all, cnorm4, tidx4);
    pass3_dist<<<2048, 256, 0, stream>>>(z, idx, cent, cnorm4, tidx4, dsum, B);
    pass4_final<<<1, 128, 0, stream>>>(dsum, cnt_all, w, out);
}